// Round 23
// baseline (164.397 us; speedup 1.0000x reference)
//
#include <hip/hip_runtime.h>
#include <hip/hip_bf16.h>

#define NN 100000
#define NE 3200000
#define NF 512
#define NH 16
#define NC 16
#define EPSF 1e-12f

// Mod-partitioned buckets: bucket = dst & 511. local = dst >> 9.
#define NBK 512
#define RCAP 7296
#define PCAP (RCAP + 256)
#define BCAP 24
#define NTILE 6250          // NN/16 exactly

// Fused feat+bin kernel geometry: 16 groups x (49 feat + 32 bin) = 1296 blocks.
#define FB_GROUPS 16
#define FB_FEAT_PG 49
#define FB_BIN_PG 32
#define FB_PER_G (FB_FEAT_PG + FB_BIN_PG)   // 81
#define BIN_T 512
#define BIN_PERBLK 6250     // NE / 512

typedef unsigned short u16;
typedef unsigned int u32;
typedef __attribute__((ext_vector_type(8))) short bf16x8;
typedef __attribute__((ext_vector_type(4))) float f32x4;

__device__ __forceinline__ u16 f2bf(float f) {
  u32 u = __float_as_uint(f);
  u += 0x7fffu + ((u >> 16) & 1u);   // round-to-nearest-even
  return (u16)(u >> 16);
}
__device__ __forceinline__ u32 pack2(float a, float b) {
  return (u32)f2bf(a) | ((u32)f2bf(b) << 16);
}
__device__ __forceinline__ void unpack8(uint4 q, float* f) {
  f[0] = __uint_as_float(q.x << 16); f[1] = __uint_as_float(q.x & 0xffff0000u);
  f[2] = __uint_as_float(q.y << 16); f[3] = __uint_as_float(q.y & 0xffff0000u);
  f[4] = __uint_as_float(q.z << 16); f[5] = __uint_as_float(q.z & 0xffff0000u);
  f[6] = __uint_as_float(q.w << 16); f[7] = __uint_as_float(q.w & 0xffff0000u);
}

// ---------------- k_init: bcur fixed-region cursors --------------------------
__global__ void k_init(int* __restrict__ bcur) {
  const int g = blockIdx.x * 256 + threadIdx.x;
  if (g < NBK) bcur[g] = g * RCAP;
}

// ---------------- k_fb: fused feat (MFMA) + bin (LDS line staging) -----------
__global__ __launch_bounds__(512) void k_fb(const float* __restrict__ x,
    const float* __restrict__ W1, const float* __restrict__ b1,
    u32* __restrict__ hh, float* __restrict__ rn,
    const int* __restrict__ srcs, const int* __restrict__ dsts,
    int* __restrict__ bcur, u32* __restrict__ stg) {
  __shared__ u32 buf[NBK][BCAP];      // 48 KB (bin blocks only)
  __shared__ int cnt[NBK];
  const int tid = threadIdx.x;
  const int grp = blockIdx.x / FB_PER_G;
  const int r = blockIdx.x % FB_PER_G;

  if (r < FB_FEAT_PG) {
    // ---- feat: wave = one 16-row tile; W1 in 16 B-frags; 1 MFMA / 32-k ----
    const int fidx = grp * FB_FEAT_PG + r;
    const int lane = tid & 63;
    const int wv = tid >> 6;          // 0..7
    const int n = lane & 15;
    const int kb = lane >> 4;

    union AB { u32 u[4]; bf16x8 v; };
    AB bf[16];
    #pragma unroll
    for (int s = 0; s < 16; ++s) {
      const int k0 = s * 32 + kb * 8;
      #pragma unroll
      for (int d = 0; d < 4; ++d)
        bf[s].u[d] = pack2(W1[(size_t)(k0 + 2 * d) * NH + n],
                           W1[(size_t)(k0 + 2 * d + 1) * NH + n]);
    }
    const float b1n = b1[n];

    const int tile = fidx * 8 + wv;
    if (tile < NTILE) {
      const float* xr = x + (size_t)(tile * 16 + n) * NF + kb * 8;
      f32x4 acc = {0.f, 0.f, 0.f, 0.f};
      #pragma unroll
      for (int s = 0; s < 16; ++s) {
        const float4 v0 = *(const float4*)(xr + s * 32);
        const float4 v1 = *(const float4*)(xr + s * 32 + 4);
        AB a;
        a.u[0] = pack2(v0.x, v0.y);
        a.u[1] = pack2(v0.z, v0.w);
        a.u[2] = pack2(v1.x, v1.y);
        a.u[3] = pack2(v1.z, v1.w);
        acc = __builtin_amdgcn_mfma_f32_16x16x32_bf16(a.v, bf[s].v, acc, 0, 0, 0);
      }
      float o[4];
      #pragma unroll
      for (int i = 0; i < 4; ++i) o[i] = fmaxf(acc[i] + b1n, 0.f);
      #pragma unroll
      for (int i = 0; i < 4; ++i) {
        float ss = o[i] * o[i];
        ss += __shfl_xor(ss, 1, 64);
        ss += __shfl_xor(ss, 2, 64);
        ss += __shfl_xor(ss, 4, 64);
        ss += __shfl_xor(ss, 8, 64);
        const int rr = tile * 16 + kb * 4 + i;
        ((u16*)hh)[(size_t)rr * 16 + n] = f2bf(o[i]);
        if (n == 0) rn[rr] = 1.0f / fmaxf(sqrtf(ss), EPSF);
      }
    }
  } else {
    // ---- bin: entry = (src << 8) | (dst >> 9); bucket = dst & 511 ----
    const int binidx = grp * FB_BIN_PG + (r - FB_FEAT_PG);
    for (int i = tid; i < NBK; i += BIN_T) cnt[i] = 0;
    __syncthreads();
    const int e0 = binidx * BIN_PERBLK;
    const int e1 = (e0 + BIN_PERBLK < NE) ? e0 + BIN_PERBLK : NE;
    for (int base = e0; base < e1; base += BIN_T) {
      const int e = base + tid;
      if (e < e1) {
        const int d = dsts[e];
        const u32 pv = ((u32)srcs[e] << 8) | (u32)(d >> 9);
        const int b = d & (NBK - 1);
        const int slot = atomicAdd(&cnt[b], 1);
        if (slot < BCAP) {
          buf[b][slot] = pv;
        } else {                        // ~never: single-entry spill
          const int g2 = atomicAdd(&bcur[b], 1);
          if (g2 < (b + 1) * RCAP) stg[g2] = pv;
          atomicSub(&cnt[b], 1);
        }
      }
      __syncthreads();
      for (int b = tid; b < NBK; b += BIN_T) {  // flush full 64B lines
        int c = cnt[b];
        while (c >= 16) {
          const int g2 = atomicAdd(&bcur[b], 16);
          if (g2 + 16 <= (b + 1) * RCAP) {
            #pragma unroll
            for (int t = 0; t < 16; t += 4)
              *(uint4*)&stg[g2 + t] = make_uint4(buf[b][c - 16 + t], buf[b][c - 15 + t],
                                                 buf[b][c - 14 + t], buf[b][c - 13 + t]);
          }
          c -= 16;
        }
        cnt[b] = c;
      }
      __syncthreads();
    }
    for (int b = tid; b < NBK; b += BIN_T) {    // exact-count partial tail
      const int c = cnt[b];
      if (c > 0) {
        const int g2 = atomicAdd(&bcur[b], c);
        if (g2 + c <= (b + 1) * RCAP)
          for (int t = 0; t < c; ++t) stg[g2 + t] = buf[b][t];
      }
    }
  }
}

// ---------------- k_sort: mod-bucket counting-sort -> csrg/nbase/ndeg --------
// Sort-only (prop1 split out to k_p1 for 8-thr/node + ILP at high occupancy).
__global__ __launch_bounds__(1024) void k_sort(const u32* __restrict__ stg,
    const int* __restrict__ bcur, u32* __restrict__ csrg,
    int* __restrict__ nbase, int* __restrict__ ndeg) {
  __shared__ u32 srt[PCAP];             // 30.2 KB
  __shared__ int sm[256];
  __shared__ int lbase[256];
  __shared__ int lcur[256];

  const int tid = threadIdx.x;
  const int b = blockIdx.x;
  const int nloc = (NN - 1 - b) / NBK + 1;   // 195 or 196
  const int s0 = b * RCAP;
  int ecnt = bcur[b] - s0;
  if (ecnt > RCAP) ecnt = RCAP;
  const int cb = b * PCAP;

  if (tid < 256) sm[tid] = 0;
  __syncthreads();

  for (int i = tid; i < ecnt; i += 1024)              // per-node count
    atomicAdd(&sm[stg[s0 + i] & 255u], 1);
  __syncthreads();

  int myc = 0;                                         // scan of (cnt+1)
  if (tid < 256) { myc = sm[tid]; sm[tid] = myc + 1; }
  __syncthreads();
  for (int s = 1; s < 256; s <<= 1) {
    int t = (tid < 256 && tid >= s) ? sm[tid - s] : 0;
    __syncthreads();
    if (tid < 256) sm[tid] += t;
    __syncthreads();
  }
  if (tid < 256) {
    const int ex = sm[tid] - (myc + 1);
    lbase[tid] = ex;
    lcur[tid] = ex;
  }
  __syncthreads();

  for (int i = tid; i < ecnt; i += 1024) {            // scatter-sort into LDS
    const u32 v = stg[s0 + i];
    const int slot = atomicAdd(&lcur[v & 255u], 1);
    if (slot < PCAP) srt[slot] = v >> 8;
  }
  __syncthreads();

  int tot = sm[255];                                   // flush sorted list
  if (tot > PCAP) tot = PCAP;
  for (int i = tid; i < tot; i += 1024) csrg[cb + i] = srt[i];
  if (tid < nloc) {
    nbase[b + tid * NBK] = cb + lbase[tid];
    ndeg[b + tid * NBK] = lcur[tid] - lbase[tid];
  }
}

// Edge body: full 16-dim dot + exp + accumulate for one src.
#define EDGE_BODY(RNS)                                                      \
  {                                                                         \
    float hs[16];                                                           \
    unpack8(q0_, hs); unpack8(q1_, hs + 8);                                 \
    float p0 = 0.f, p1 = 0.f, p2 = 0.f, p3 = 0.f;                           \
    _Pragma("unroll")                                                       \
    for (int k = 0; k < 4; ++k) {                                           \
      p0 = fmaf(hs[k],      hd[k],      p0);                                \
      p1 = fmaf(hs[k + 4],  hd[k + 4],  p1);                                \
      p2 = fmaf(hs[k + 8],  hd[k + 8],  p2);                                \
      p3 = fmaf(hs[k + 12], hd[k + 12], p3);                                \
    }                                                                       \
    const float p = (p0 + p1) + (p2 + p3);                                  \
    const float w = __expf(brd * (RNS) * p);                                \
    _Pragma("unroll")                                                       \
    for (int k = 0; k < 16; ++k) acc[k] = fmaf(w, hs[k], acc[k]);           \
    ssum += w;                                                              \
  }

// Shared gather loop: 8 threads/node (es), 2-edge ILP, virtual self-loop.
#define GATHER_LOOP(HTAB, RNTAB)                                            \
  int i = es;                                                               \
  for (; i + 8 < deg; i += 16) {                                            \
    const int sA = (int)csrg[off + i];                                      \
    const int sB = (int)csrg[off + i + 8];                                  \
    const uint4 a0 = *(const uint4*)(HTAB + (size_t)sA * 8);                \
    const uint4 a1 = *(const uint4*)(HTAB + (size_t)sA * 8 + 4);            \
    const uint4 b0 = *(const uint4*)(HTAB + (size_t)sB * 8);                \
    const uint4 b1v = *(const uint4*)(HTAB + (size_t)sB * 8 + 4);           \
    const float rnsA = RNTAB[sA];                                           \
    const float rnsB = RNTAB[sB];                                           \
    { const uint4 q0_ = a0, q1_ = a1; EDGE_BODY(rnsA); }                    \
    { const uint4 q0_ = b0, q1_ = b1v; EDGE_BODY(rnsB); }                   \
  }                                                                         \
  for (; i < deg + 1; i += 8) {                                             \
    uint4 q0_, q1_;                                                         \
    float rns;                                                              \
    if (i < deg) {                                                          \
      const int src = (int)csrg[off + i];                                   \
      q0_ = *(const uint4*)(HTAB + (size_t)src * 8);                        \
      q1_ = *(const uint4*)(HTAB + (size_t)src * 8 + 4);                    \
      rns = RNTAB[src];                                                     \
    } else {                                                                \
      q0_ = d0; q1_ = d1; rns = rv;                                         \
    }                                                                       \
    EDGE_BODY(rns);                                                         \
  }

// ---------------- k_p1: prop1 (beta=1), 8 threads/node + 2-ILP ---------------
__global__ __launch_bounds__(256) void k_p1(const u32* __restrict__ h1,
    const float* __restrict__ rn1, const u32* __restrict__ csrg,
    const int* __restrict__ nbase, const int* __restrict__ ndeg,
    u32* __restrict__ h2, float* __restrict__ rn2) {
  const int t = blockIdx.x * 256 + threadIdx.x;
  const int es = t & 7;
  const int n = t >> 3;
  if (n >= NN) return;

  const u32* rp = h1 + (size_t)n * 8;
  const uint4 d0 = *(const uint4*)rp;
  const uint4 d1 = *(const uint4*)(rp + 4);
  float hd[16];
  unpack8(d0, hd); unpack8(d1, hd + 8);
  const float rv = rn1[n];
  const float brd = rv;                 // beta = 1
  const int off = nbase[n];
  const int deg = ndeg[n];

  float acc[16];
  #pragma unroll
  for (int k = 0; k < 16; ++k) acc[k] = 0.f;
  float ssum = 0.f;

  GATHER_LOOP(h1, rn1)

  #pragma unroll
  for (int k = 0; k < 16; ++k) {
    acc[k] += __shfl_xor(acc[k], 1, 64);
    acc[k] += __shfl_xor(acc[k], 2, 64);
    acc[k] += __shfl_xor(acc[k], 4, 64);
  }
  ssum += __shfl_xor(ssum, 1, 64);
  ssum += __shfl_xor(ssum, 2, 64);
  ssum += __shfl_xor(ssum, 4, 64);

  if (es == 0) {
    const float inv = 1.0f / ssum;
    float o[16];
    #pragma unroll
    for (int k = 0; k < 16; ++k) o[k] = acc[k] * inv;
    float ss2 = 0.f;
    #pragma unroll
    for (int k = 0; k < 16; ++k) ss2 = fmaf(o[k], o[k], ss2);
    const float rno = 1.0f / fmaxf(sqrtf(ss2), EPSF);
    u32* op = h2 + (size_t)n * 8;
    uint4 w0, w1;
    w0.x = pack2(o[0], o[1]);   w0.y = pack2(o[2], o[3]);
    w0.z = pack2(o[4], o[5]);   w0.w = pack2(o[6], o[7]);
    w1.x = pack2(o[8], o[9]);   w1.y = pack2(o[10], o[11]);
    w1.z = pack2(o[12], o[13]); w1.w = pack2(o[14], o[15]);
    *(uint4*)op = w0;
    *(uint4*)(op + 4) = w1;
    rn2[n] = rno;
  }
}

// ---------------- k_sp2: prop2 + W2 + log_softmax, 8 threads/node + 2-ILP ----
__global__ __launch_bounds__(256) void k_sp2(const u32* __restrict__ hh,
    const float* __restrict__ rn, const u32* __restrict__ csrg,
    const int* __restrict__ nbase, const int* __restrict__ ndeg,
    const float* __restrict__ betap, const float* __restrict__ W2,
    const float* __restrict__ b2, float* __restrict__ out) {
  const int t = blockIdx.x * 256 + threadIdx.x;
  const int es = t & 7;
  const int n = t >> 3;
  if (n >= NN) return;
  const float beta = betap[0];

  const u32* rp = hh + (size_t)n * 8;
  const uint4 d0 = *(const uint4*)rp;
  const uint4 d1 = *(const uint4*)(rp + 4);
  float hd[16];
  unpack8(d0, hd); unpack8(d1, hd + 8);
  const float rv = rn[n];
  const float brd = beta * rv;
  const int off = nbase[n];
  const int deg = ndeg[n];

  float acc[16];
  #pragma unroll
  for (int k = 0; k < 16; ++k) acc[k] = 0.f;
  float ssum = 0.f;

  GATHER_LOOP(hh, rn)

  #pragma unroll
  for (int k = 0; k < 16; ++k) {
    acc[k] += __shfl_xor(acc[k], 1, 64);
    acc[k] += __shfl_xor(acc[k], 2, 64);
    acc[k] += __shfl_xor(acc[k], 4, 64);
  }
  ssum += __shfl_xor(ssum, 1, 64);
  ssum += __shfl_xor(ssum, 2, 64);
  ssum += __shfl_xor(ssum, 4, 64);
  const float inv = 1.0f / ssum;
  float o[16];
  #pragma unroll
  for (int k = 0; k < 16; ++k) o[k] = acc[k] * inv;

  float lg[2];
  #pragma unroll
  for (int jj = 0; jj < 2; ++jj) {
    const int j = es * 2 + jj;
    float a = b2[j];
    #pragma unroll
    for (int k = 0; k < 16; ++k) a = fmaf(o[k], W2[k * NC + j], a);
    lg[jj] = a;
  }
  float m = fmaxf(lg[0], lg[1]);
  m = fmaxf(m, __shfl_xor(m, 1, 64));
  m = fmaxf(m, __shfl_xor(m, 2, 64));
  m = fmaxf(m, __shfl_xor(m, 4, 64));
  float se = __expf(lg[0] - m) + __expf(lg[1] - m);
  se += __shfl_xor(se, 1, 64);
  se += __shfl_xor(se, 2, 64);
  se += __shfl_xor(se, 4, 64);
  const float ls = m + __logf(se);
  *(float2*)(out + (size_t)n * NC + es * 2) = make_float2(lg[0] - ls, lg[1] - ls);
}

extern "C" void kernel_launch(void* const* d_in, const int* in_sizes, int n_in,
                              void* d_out, int out_size, void* d_ws, size_t ws_size,
                              hipStream_t stream) {
  const float* x     = (const float*)d_in[0];
  const int*   ei    = (const int*)d_in[1];
  const float* W1    = (const float*)d_in[2];
  const float* b1    = (const float*)d_in[3];
  const float* W2    = (const float*)d_in[4];
  const float* b2    = (const float*)d_in[5];
  const float* beta2 = (const float*)d_in[6];
  float* out = (float*)d_out;

  char* ws = (char*)d_ws;
  size_t o = 0;
  auto alloc = [&](size_t bytes) -> void* {
    o = (o + 255) & ~(size_t)255;
    void* p = ws + o;
    o += bytes;
    return p;
  };
  u32*   h1    = (u32*)alloc((size_t)NN * 8 * 4);
  u32*   h2    = (u32*)alloc((size_t)NN * 8 * 4);
  float* rn1   = (float*)alloc((size_t)NN * 4);
  float* rn2   = (float*)alloc((size_t)NN * 4);
  u32*   stg   = (u32*)alloc((size_t)NBK * RCAP * 4);
  u32*   csrg  = (u32*)alloc((size_t)NBK * PCAP * 4);
  int*   nbase = (int*)alloc((size_t)NN * 4);
  int*   ndeg  = (int*)alloc((size_t)NN * 4);
  int*   bcur  = (int*)alloc((size_t)NBK * 4);

  const int* esrc = ei;
  const int* edst = ei + NE;
  const int nprop = (NN * 8 + 255) / 256;  // 3125

  k_init<<<2, 256, 0, stream>>>(bcur);
  k_fb<<<FB_GROUPS * FB_PER_G, 512, 0, stream>>>(x, W1, b1, h1, rn1,
                                                 esrc, edst, bcur, stg);
  k_sort<<<NBK, 1024, 0, stream>>>(stg, bcur, csrg, nbase, ndeg);
  k_p1<<<nprop, 256, 0, stream>>>(h1, rn1, csrg, nbase, ndeg, h2, rn2);
  k_sp2<<<nprop, 256, 0, stream>>>(h2, rn2, csrg, nbase, ndeg, beta2, W2, b2, out);
}

// Round 24
// 157.763 us; speedup vs baseline: 1.0421x; 1.0421x over previous
//
#include <hip/hip_runtime.h>
#include <hip/hip_bf16.h>

#define NN 100000
#define NE 3200000
#define NF 512
#define NH 16
#define NC 16
#define EPSF 1e-12f

// Mod-partitioned buckets: bucket = dst & 511. local = dst >> 9.
#define NBK 512
#define RCAP 7296
#define PCAP (RCAP + 256)
#define BCAP 24
#define NTILE 6250          // NN/16 exactly

// Fused feat+bin kernel geometry: 16 groups x (49 feat + 32 bin) = 1296 blocks.
#define FB_GROUPS 16
#define FB_FEAT_PG 49       // 784 feat blocks x 8 waves = 6272 tile slots >= 6250
#define FB_BIN_PG 32        // 512 bin blocks
#define FB_PER_G (FB_FEAT_PG + FB_BIN_PG)   // 81
#define BIN_T 512
#define BIN_PERBLK 6250     // NE / 512

typedef unsigned short u16;
typedef unsigned int u32;
typedef __attribute__((ext_vector_type(8))) short bf16x8;
typedef __attribute__((ext_vector_type(4))) float f32x4;

__device__ __forceinline__ u16 f2bf(float f) {
  u32 u = __float_as_uint(f);
  u += 0x7fffu + ((u >> 16) & 1u);   // round-to-nearest-even
  return (u16)(u >> 16);
}
__device__ __forceinline__ u32 pack2(float a, float b) {
  return (u32)f2bf(a) | ((u32)f2bf(b) << 16);
}
__device__ __forceinline__ void unpack8(uint4 q, float* f) {
  f[0] = __uint_as_float(q.x << 16); f[1] = __uint_as_float(q.x & 0xffff0000u);
  f[2] = __uint_as_float(q.y << 16); f[3] = __uint_as_float(q.y & 0xffff0000u);
  f[4] = __uint_as_float(q.z << 16); f[5] = __uint_as_float(q.z & 0xffff0000u);
  f[6] = __uint_as_float(q.w << 16); f[7] = __uint_as_float(q.w & 0xffff0000u);
}

// ---------------- k_init: bcur fixed-region cursors --------------------------
__global__ void k_init(int* __restrict__ bcur) {
  const int g = blockIdx.x * 256 + threadIdx.x;
  if (g < NBK) bcur[g] = g * RCAP;
}

// ---------------- k_fb: fused feat (MFMA) + bin (LDS line staging) -----------
// Interleaved block types overlap x-streaming (feat) with edge binning (bin).
__global__ __launch_bounds__(512) void k_fb(const float* __restrict__ x,
    const float* __restrict__ W1, const float* __restrict__ b1,
    u32* __restrict__ hh, float* __restrict__ rn,
    const int* __restrict__ srcs, const int* __restrict__ dsts,
    int* __restrict__ bcur, u32* __restrict__ stg) {
  __shared__ u32 buf[NBK][BCAP];      // 48 KB (bin blocks only)
  __shared__ int cnt[NBK];
  const int tid = threadIdx.x;
  const int grp = blockIdx.x / FB_PER_G;
  const int r = blockIdx.x % FB_PER_G;

  if (r < FB_FEAT_PG) {
    // ---- feat: wave = one 16-row tile; W1 in 16 B-frags; 1 MFMA / 32-k ----
    const int fidx = grp * FB_FEAT_PG + r;
    const int lane = tid & 63;
    const int wv = tid >> 6;          // 0..7
    const int n = lane & 15;
    const int kb = lane >> 4;

    union AB { u32 u[4]; bf16x8 v; };
    AB bf[16];
    #pragma unroll
    for (int s = 0; s < 16; ++s) {
      const int k0 = s * 32 + kb * 8;
      #pragma unroll
      for (int d = 0; d < 4; ++d)
        bf[s].u[d] = pack2(W1[(size_t)(k0 + 2 * d) * NH + n],
                           W1[(size_t)(k0 + 2 * d + 1) * NH + n]);
    }
    const float b1n = b1[n];

    const int tile = fidx * 8 + wv;
    if (tile < NTILE) {
      const float* xr = x + (size_t)(tile * 16 + n) * NF + kb * 8;
      f32x4 acc = {0.f, 0.f, 0.f, 0.f};
      #pragma unroll
      for (int s = 0; s < 16; ++s) {
        const float4 v0 = *(const float4*)(xr + s * 32);
        const float4 v1 = *(const float4*)(xr + s * 32 + 4);
        AB a;
        a.u[0] = pack2(v0.x, v0.y);
        a.u[1] = pack2(v0.z, v0.w);
        a.u[2] = pack2(v1.x, v1.y);
        a.u[3] = pack2(v1.z, v1.w);
        acc = __builtin_amdgcn_mfma_f32_16x16x32_bf16(a.v, bf[s].v, acc, 0, 0, 0);
      }
      float o[4];
      #pragma unroll
      for (int i = 0; i < 4; ++i) o[i] = fmaxf(acc[i] + b1n, 0.f);
      #pragma unroll
      for (int i = 0; i < 4; ++i) {
        float ss = o[i] * o[i];
        ss += __shfl_xor(ss, 1, 64);
        ss += __shfl_xor(ss, 2, 64);
        ss += __shfl_xor(ss, 4, 64);
        ss += __shfl_xor(ss, 8, 64);
        const int rr = tile * 16 + kb * 4 + i;
        ((u16*)hh)[(size_t)rr * 16 + n] = f2bf(o[i]);
        if (n == 0) rn[rr] = 1.0f / fmaxf(sqrtf(ss), EPSF);
      }
    }
  } else {
    // ---- bin: entry = (src << 8) | (dst >> 9); bucket = dst & 511 ----
    const int binidx = grp * FB_BIN_PG + (r - FB_FEAT_PG);
    for (int i = tid; i < NBK; i += BIN_T) cnt[i] = 0;
    __syncthreads();
    const int e0 = binidx * BIN_PERBLK;
    const int e1 = (e0 + BIN_PERBLK < NE) ? e0 + BIN_PERBLK : NE;
    for (int base = e0; base < e1; base += BIN_T) {
      const int e = base + tid;
      if (e < e1) {
        const int d = dsts[e];
        const u32 pv = ((u32)srcs[e] << 8) | (u32)(d >> 9);
        const int b = d & (NBK - 1);
        const int slot = atomicAdd(&cnt[b], 1);
        if (slot < BCAP) {
          buf[b][slot] = pv;
        } else {                        // ~never: single-entry spill
          const int g2 = atomicAdd(&bcur[b], 1);
          if (g2 < (b + 1) * RCAP) stg[g2] = pv;
          atomicSub(&cnt[b], 1);
        }
      }
      __syncthreads();
      for (int b = tid; b < NBK; b += BIN_T) {  // flush full 64B lines
        int c = cnt[b];
        while (c >= 16) {
          const int g2 = atomicAdd(&bcur[b], 16);
          if (g2 + 16 <= (b + 1) * RCAP) {
            #pragma unroll
            for (int t = 0; t < 16; t += 4)
              *(uint4*)&stg[g2 + t] = make_uint4(buf[b][c - 16 + t], buf[b][c - 15 + t],
                                                 buf[b][c - 14 + t], buf[b][c - 13 + t]);
          }
          c -= 16;
        }
        cnt[b] = c;
      }
      __syncthreads();
    }
    for (int b = tid; b < NBK; b += BIN_T) {    // exact-count partial tail
      const int c = cnt[b];
      if (c > 0) {
        const int g2 = atomicAdd(&bcur[b], c);
        if (g2 + c <= (b + 1) * RCAP)
          for (int t = 0; t < c; ++t) stg[g2 + t] = buf[b][t];
      }
    }
  }
}

// ---------------- k_sp1: mod-bucket counting-sort + prop1 (beta=1) fused -----
__global__ __launch_bounds__(1024) void k_sp1(const u32* __restrict__ h1,
    const float* __restrict__ rn1, const u32* __restrict__ stg,
    const int* __restrict__ bcur, u32* __restrict__ h2, float* __restrict__ rn2,
    u32* __restrict__ csrg, int* __restrict__ nbase, int* __restrict__ ndeg) {
  __shared__ u32 srt[PCAP];             // 30.2 KB
  __shared__ int sm[256];
  __shared__ int lbase[256];
  __shared__ int lcur[256];

  const int tid = threadIdx.x;
  const int b = blockIdx.x;
  const int nloc = (NN - 1 - b) / NBK + 1;   // 195 or 196
  const int s0 = b * RCAP;
  int ecnt = bcur[b] - s0;
  if (ecnt > RCAP) ecnt = RCAP;
  const int cb = b * PCAP;

  if (tid < 256) sm[tid] = 0;
  __syncthreads();

  for (int i = tid; i < ecnt; i += 1024)              // per-node count
    atomicAdd(&sm[stg[s0 + i] & 255u], 1);
  __syncthreads();

  int myc = 0;                                         // scan of (cnt+1)
  if (tid < 256) { myc = sm[tid]; sm[tid] = myc + 1; }
  __syncthreads();
  for (int s = 1; s < 256; s <<= 1) {
    int t = (tid < 256 && tid >= s) ? sm[tid - s] : 0;
    __syncthreads();
    if (tid < 256) sm[tid] += t;
    __syncthreads();
  }
  if (tid < 256) {
    const int ex = sm[tid] - (myc + 1);
    lbase[tid] = ex;
    lcur[tid] = ex;
  }
  __syncthreads();

  for (int i = tid; i < ecnt; i += 1024) {            // scatter-sort into LDS
    const u32 v = stg[s0 + i];
    const int slot = atomicAdd(&lcur[v & 255u], 1);
    if (slot < PCAP) srt[slot] = v >> 8;
  }
  __syncthreads();

  int tot = sm[255];                                   // flush sorted list
  if (tot > PCAP) tot = PCAP;
  for (int i = tid; i < tot; i += 1024) csrg[cb + i] = srt[i];
  if (tid < nloc) {
    nbase[b + tid * NBK] = cb + lbase[tid];
    ndeg[b + tid * NBK] = lcur[tid] - lbase[tid];
  }

  // ---- prop1 compute: 4 threads/node, edges from LDS srt ----
  const int nl = tid >> 2;
  const int es = tid & 3;
  if (nl < nloc) {
    const int n = b + nl * NBK;
    const u32* rp = h1 + (size_t)n * 8;
    const uint4 d0 = *(const uint4*)rp;
    const uint4 d1 = *(const uint4*)(rp + 4);
    float hd[16];
    unpack8(d0, hd); unpack8(d1, hd + 8);
    const float rv = rn1[n];
    const int off = lbase[nl];
    const int deg = lcur[nl] - lbase[nl];

    float acc[16];
    #pragma unroll
    for (int k = 0; k < 16; ++k) acc[k] = 0.f;
    float ssum = 0.f;

    for (int i = es; i < deg + 1; i += 4) {           // +1 virtual self-loop
      float hs[16], rns;
      if (i < deg) {
        const int src = (int)srt[off + i];
        const u32* sp = h1 + (size_t)src * 8;
        const uint4 q0 = *(const uint4*)sp;
        const uint4 q1 = *(const uint4*)(sp + 4);
        unpack8(q0, hs); unpack8(q1, hs + 8);
        rns = rn1[src];
      } else {
        #pragma unroll
        for (int k = 0; k < 16; ++k) hs[k] = hd[k];
        rns = rv;
      }
      float p0 = 0.f, p1 = 0.f, p2 = 0.f, p3 = 0.f;
      #pragma unroll
      for (int k = 0; k < 4; ++k) {
        p0 = fmaf(hs[k],      hd[k],      p0);
        p1 = fmaf(hs[k + 4],  hd[k + 4],  p1);
        p2 = fmaf(hs[k + 8],  hd[k + 8],  p2);
        p3 = fmaf(hs[k + 12], hd[k + 12], p3);
      }
      const float p = (p0 + p1) + (p2 + p3);
      const float w = __expf(rv * rns * p);           // beta = 1
      #pragma unroll
      for (int k = 0; k < 16; ++k) acc[k] = fmaf(w, hs[k], acc[k]);
      ssum += w;
    }

    #pragma unroll
    for (int k = 0; k < 16; ++k) {
      acc[k] += __shfl_xor(acc[k], 1, 64);
      acc[k] += __shfl_xor(acc[k], 2, 64);
    }
    ssum += __shfl_xor(ssum, 1, 64);
    ssum += __shfl_xor(ssum, 2, 64);

    if (es == 0) {
      const float inv = 1.0f / ssum;
      float o[16];
      #pragma unroll
      for (int k = 0; k < 16; ++k) o[k] = acc[k] * inv;
      float ss2 = 0.f;
      #pragma unroll
      for (int k = 0; k < 16; ++k) ss2 = fmaf(o[k], o[k], ss2);
      const float rno = 1.0f / fmaxf(sqrtf(ss2), EPSF);
      u32* op = h2 + (size_t)n * 8;
      uint4 w0, w1;
      w0.x = pack2(o[0], o[1]);   w0.y = pack2(o[2], o[3]);
      w0.z = pack2(o[4], o[5]);   w0.w = pack2(o[6], o[7]);
      w1.x = pack2(o[8], o[9]);   w1.y = pack2(o[10], o[11]);
      w1.z = pack2(o[12], o[13]); w1.w = pack2(o[14], o[15]);
      *(uint4*)op = w0;
      *(uint4*)(op + 4) = w1;
      rn2[n] = rno;
    }
  }
}

// Edge body for sp2's ILP loop: full 16-dim dot + exp + accumulate.
#define EDGE_BODY(RNS)                                                      \
  {                                                                         \
    float hs[16];                                                           \
    unpack8(q0_, hs); unpack8(q1_, hs + 8);                                 \
    float p0 = 0.f, p1 = 0.f, p2 = 0.f, p3 = 0.f;                           \
    _Pragma("unroll")                                                       \
    for (int k = 0; k < 4; ++k) {                                           \
      p0 = fmaf(hs[k],      hd[k],      p0);                                \
      p1 = fmaf(hs[k + 4],  hd[k + 4],  p1);                                \
      p2 = fmaf(hs[k + 8],  hd[k + 8],  p2);                                \
      p3 = fmaf(hs[k + 12], hd[k + 12], p3);                                \
    }                                                                       \
    const float p = (p0 + p1) + (p2 + p3);                                  \
    const float w = __expf(brd * (RNS) * p);                                \
    _Pragma("unroll")                                                       \
    for (int k = 0; k < 16; ++k) acc[k] = fmaf(w, hs[k], acc[k]);           \
    ssum += w;                                                              \
  }

// ---------------- k_sp2: prop2 + W2 + log_softmax, 8 threads/node + 2-ILP ----
__global__ __launch_bounds__(256) void k_sp2(const u32* __restrict__ hh,
    const float* __restrict__ rn, const u32* __restrict__ csrg,
    const int* __restrict__ nbase, const int* __restrict__ ndeg,
    const float* __restrict__ betap, const float* __restrict__ W2,
    const float* __restrict__ b2, float* __restrict__ out) {
  const int t = blockIdx.x * 256 + threadIdx.x;
  const int es = t & 7;
  const int n = t >> 3;
  if (n >= NN) return;
  const float beta = betap[0];

  const u32* rp = hh + (size_t)n * 8;
  const uint4 d0 = *(const uint4*)rp;
  const uint4 d1 = *(const uint4*)(rp + 4);
  float hd[16];
  unpack8(d0, hd); unpack8(d1, hd + 8);
  const float rv = rn[n];
  const float brd = beta * rv;
  const int off = nbase[n];
  const int deg = ndeg[n];

  float acc[16];
  #pragma unroll
  for (int k = 0; k < 16; ++k) acc[k] = 0.f;
  float ssum = 0.f;

  int i = es;
  for (; i + 8 < deg; i += 16) {        // two edges in flight
    const int sA = (int)csrg[off + i];
    const int sB = (int)csrg[off + i + 8];
    const uint4 a0 = *(const uint4*)(hh + (size_t)sA * 8);
    const uint4 a1 = *(const uint4*)(hh + (size_t)sA * 8 + 4);
    const uint4 b0 = *(const uint4*)(hh + (size_t)sB * 8);
    const uint4 b1v = *(const uint4*)(hh + (size_t)sB * 8 + 4);
    const float rnsA = rn[sA];
    const float rnsB = rn[sB];
    { const uint4 q0_ = a0, q1_ = a1; EDGE_BODY(rnsA); }
    { const uint4 q0_ = b0, q1_ = b1v; EDGE_BODY(rnsB); }
  }
  for (; i < deg + 1; i += 8) {         // remainder + virtual self-loop
    uint4 q0_, q1_;
    float rns;
    if (i < deg) {
      const int src = (int)csrg[off + i];
      q0_ = *(const uint4*)(hh + (size_t)src * 8);
      q1_ = *(const uint4*)(hh + (size_t)src * 8 + 4);
      rns = rn[src];
    } else {
      q0_ = d0; q1_ = d1; rns = rv;
    }
    EDGE_BODY(rns);
  }

  #pragma unroll
  for (int k = 0; k < 16; ++k) {
    acc[k] += __shfl_xor(acc[k], 1, 64);
    acc[k] += __shfl_xor(acc[k], 2, 64);
    acc[k] += __shfl_xor(acc[k], 4, 64);
  }
  ssum += __shfl_xor(ssum, 1, 64);
  ssum += __shfl_xor(ssum, 2, 64);
  ssum += __shfl_xor(ssum, 4, 64);
  const float inv = 1.0f / ssum;
  float o[16];
  #pragma unroll
  for (int k = 0; k < 16; ++k) o[k] = acc[k] * inv;

  float lg[2];
  #pragma unroll
  for (int jj = 0; jj < 2; ++jj) {
    const int j = es * 2 + jj;
    float a = b2[j];
    #pragma unroll
    for (int k = 0; k < 16; ++k) a = fmaf(o[k], W2[k * NC + j], a);
    lg[jj] = a;
  }
  float m = fmaxf(lg[0], lg[1]);
  m = fmaxf(m, __shfl_xor(m, 1, 64));
  m = fmaxf(m, __shfl_xor(m, 2, 64));
  m = fmaxf(m, __shfl_xor(m, 4, 64));
  float se = __expf(lg[0] - m) + __expf(lg[1] - m);
  se += __shfl_xor(se, 1, 64);
  se += __shfl_xor(se, 2, 64);
  se += __shfl_xor(se, 4, 64);
  const float ls = m + __logf(se);
  *(float2*)(out + (size_t)n * NC + es * 2) = make_float2(lg[0] - ls, lg[1] - ls);
}

extern "C" void kernel_launch(void* const* d_in, const int* in_sizes, int n_in,
                              void* d_out, int out_size, void* d_ws, size_t ws_size,
                              hipStream_t stream) {
  const float* x     = (const float*)d_in[0];
  const int*   ei    = (const int*)d_in[1];
  const float* W1    = (const float*)d_in[2];
  const float* b1    = (const float*)d_in[3];
  const float* W2    = (const float*)d_in[4];
  const float* b2    = (const float*)d_in[5];
  const float* beta2 = (const float*)d_in[6];
  float* out = (float*)d_out;

  char* ws = (char*)d_ws;
  size_t o = 0;
  auto alloc = [&](size_t bytes) -> void* {
    o = (o + 255) & ~(size_t)255;
    void* p = ws + o;
    o += bytes;
    return p;
  };
  u32*   h1    = (u32*)alloc((size_t)NN * 8 * 4);
  u32*   h2    = (u32*)alloc((size_t)NN * 8 * 4);
  float* rn1   = (float*)alloc((size_t)NN * 4);
  float* rn2   = (float*)alloc((size_t)NN * 4);
  u32*   stg   = (u32*)alloc((size_t)NBK * RCAP * 4);
  u32*   csrg  = (u32*)alloc((size_t)NBK * PCAP * 4);
  int*   nbase = (int*)alloc((size_t)NN * 4);
  int*   ndeg  = (int*)alloc((size_t)NN * 4);
  int*   bcur  = (int*)alloc((size_t)NBK * 4);

  const int* esrc = ei;
  const int* edst = ei + NE;
  const int nsp2 = (NN * 8 + 255) / 256;  // 3125

  k_init<<<2, 256, 0, stream>>>(bcur);
  k_fb<<<FB_GROUPS * FB_PER_G, 512, 0, stream>>>(x, W1, b1, h1, rn1,
                                                 esrc, edst, bcur, stg);
  k_sp1<<<NBK, 1024, 0, stream>>>(h1, rn1, stg, bcur, h2, rn2, csrg, nbase, ndeg);
  k_sp2<<<nsp2, 256, 0, stream>>>(h2, rn2, csrg, nbase, ndeg, beta2, W2, b2, out);
}